// Round 13
// baseline (192.996 us; speedup 1.0000x reference)
//
#include <hip/hip_runtime.h>

// GNN surrogate — f16 MFMA, FOUR batches per wave (4-way ILP), 1 wave/block.
// r12 (2-way ILP) confirmed the latency-bound ILP theory: 150->113 us. This
// doubles the independent chains per instruction stream. block=64, LDS
// 4x9728=38912 B -> 4 blocks/CU = 4 waves/CU = 16 concurrent batch chains.
// __launch_bounds__(64,1) -> 512-VGPR budget (peak live ~230, no spill).
// adjf B-frags + weights now amortized over 4 batches per load.
// Folds (exact): M_l = W2[l]@W1[l+1] (adj row-normalized -> biases commute
// through aggregation), lift absorbed into W1eff (K=3 pad 32),
// v[j]=mean_i adj[i,j], u=W2[2]@W_ro, cp=(b2[2]·W_ro)*sum(v)+b_ro.

typedef _Float16 f16;
typedef __attribute__((ext_vector_type(8))) _Float16 half8;
typedef __attribute__((ext_vector_type(4))) _Float16 half4;
typedef __attribute__((ext_vector_type(2))) __fp16 fp16x2;   // cvt_pkrtz native
typedef __attribute__((ext_vector_type(4))) float f32x4;

namespace {
constexpr int N = 128, H = 32;
// ws byte layout
constexpr int WS_ADJF = 0;       // f16 [128][128] adj row-major        (32768 B)
constexpr int WS_WFB  = 32768;   // f16 [3][2][64][8] B-frag-ordered Meff (6144 B)
constexpr int WS_BIAS = 38912;   // f32 [3][32] folded biases            (384 B)
constexpr int WS_V    = 39424;   // f32 [128] v[j]=mean_i adj[i][j]      (512 B)
constexpr int WS_U    = 39936;   // f32 [32]  u[k]=sum_c W2[2][k][c]W_ro (128 B)
constexpr int WS_C    = 40064;   // f32 [1]
constexpr int TS = 152;  // bufT row stride f16 (304 B; 76w step ≡12 mod 32)
constexpr int PS = 36;   // bufP row stride f16 (72 B; 18w step, distinct banks)
constexpr int SLAB = 4864;       // f16 per slab = 9728 B
}

static __device__ __forceinline__ half4 pk4(float a, float b, float c, float d) {
  union { half4 v; fp16x2 h[2]; } u;
  u.h[0] = __builtin_amdgcn_cvt_pkrtz(a, b);
  u.h[1] = __builtin_amdgcn_cvt_pkrtz(c, d);
  return u.v;
}
static __device__ __forceinline__ half4 relu4(half4 v) {
  const half4 z = {};
  return __builtin_elementwise_max(v, z);
}
// bufP half8 read as 2x b64 (rows 8B-aligned)
static __device__ __forceinline__ half8 ldp(const f16* slab, int row, int quad) {
  union { half8 v; half4 h[2]; } u;
  u.h[0] = *(const half4*)(slab + row * PS + quad * 8);
  u.h[1] = *(const half4*)(slab + row * PS + quad * 8 + 4);
  return u.v;
}

// ---- single-block prep: adj->f16, folded weights/biases, v, u, cp ----
__global__ void prep(const float* __restrict__ adj,
                     const float* __restrict__ W_lift,
                     const float* __restrict__ b_lift,
                     const float* __restrict__ W1,
                     const float* __restrict__ b1,
                     const float* __restrict__ W2,
                     const float* __restrict__ b2,
                     const float* __restrict__ W_ro,
                     const float* __restrict__ b_ro,
                     char* __restrict__ ws) {
  const int tid = threadIdx.x;
  f16* adjf  = (f16*)(ws + WS_ADJF);
  f16* wfb   = (f16*)(ws + WS_WFB);
  float* bia = (float*)(ws + WS_BIAS);
  float* v   = (float*)(ws + WS_V);
  float* u   = (float*)(ws + WS_U);
  float* cp  = (float*)(ws + WS_C);

  {
    const float4* a4 = (const float4*)adj;
#pragma unroll
    for (int r = 0; r < 8; ++r) {
      const int idx = r * 512 + tid * 2;
      const float4 p = a4[idx], q = a4[idx + 1];
      union { half8 v8; fp16x2 h[4]; } o;
      o.h[0] = __builtin_amdgcn_cvt_pkrtz(p.x, p.y);
      o.h[1] = __builtin_amdgcn_cvt_pkrtz(p.z, p.w);
      o.h[2] = __builtin_amdgcn_cvt_pkrtz(q.x, q.y);
      o.h[3] = __builtin_amdgcn_cvt_pkrtz(q.z, q.w);
      *(half8*)(adjf + idx * 4) = o.v8;
    }
  }

  __shared__ float tmp[3][H][H];
  __shared__ float sred[N];
  for (int idx = tid; idx < 3 * H * H; idx += 256) {
    const int l = idx >> 10, rem = idx & 1023;
    const int k = rem >> 5, fo = rem & 31;
    float val = 0.f;
    if (l == 0) {
      if (k < 3) for (int c = 0; c < H; ++c) val += W_lift[k * H + c] * W1[c * H + fo];
    } else {
      const float* w2l = W2 + (l - 1) * H * H;
      const float* w1n = W1 + l * H * H;
      for (int c = 0; c < H; ++c) val += w2l[k * H + c] * w1n[c * H + fo];
    }
    tmp[l][k][fo] = val;
  }
  if (tid < N) {
    float s = 0.f;
    for (int i = 0; i < N; ++i) s += adj[i * N + tid];
    v[tid] = s * (1.0f / N);
    sred[tid] = s * (1.0f / N);
  }
  if (tid < H) {
    float s0 = b1[tid], s1 = b1[H + tid], s2 = b1[2 * H + tid];
    for (int c = 0; c < H; ++c) {
      s0 += b_lift[c] * W1[c * H + tid];
      s1 += b2[c] * W1[H * H + c * H + tid];
      s2 += b2[H + c] * W1[2 * H * H + c * H + tid];
    }
    bia[tid] = s0; bia[H + tid] = s1; bia[2 * H + tid] = s2;
    float su = 0.f;
    for (int c = 0; c < H; ++c) su += W2[2 * H * H + tid * H + c] * W_ro[c];
    u[tid] = su;
  }
  __syncthreads();
  for (int idx = tid; idx < 3 * 1024; idx += 256) {
    const int l = idx >> 10, rem = idx & 1023;
    const int t = rem >> 9, ln = (rem >> 3) & 63, j = rem & 7;
    const int q = ln >> 4, lr = ln & 15;
    wfb[idx] = (f16)tmp[l][q * 8 + j][t * 16 + lr];
  }
  if (tid == 0) {
    float c2r = 0.f;
    for (int k = 0; k < H; ++k) c2r += b2[2 * H + k] * W_ro[k];
    float S = 0.f;
    for (int j = 0; j < N; ++j) S += sred[j];
    cp[0] = c2r * S + b_ro[0];
  }
}

__global__ __launch_bounds__(64, 1)
void gnn_mfma(const float* __restrict__ x,
              const char* __restrict__ ws,
              float* __restrict__ out) {
  __shared__ f16 smem[4][SLAB];   // 4 batch slabs, one wave owns all

  const f16* adjf  = (const f16*)(ws + WS_ADJF);
  const f16* wfb   = (const f16*)(ws + WS_WFB);
  const float* bia = (const float*)(ws + WS_BIAS);
  const float* v   = (const float*)(ws + WS_V);
  const float* u   = (const float*)(ws + WS_U);
  const float* cp  = (const float*)(ws + WS_C);

  const int lane = threadIdx.x & 63;
  const int lrow = lane & 15;
  const int quad = lane >> 4;
  const int b0   = blockIdx.x * 4;

  const f32x4 zero = {0.f, 0.f, 0.f, 0.f};

  // ---- L0: T = relu(x·W1eff + b0) for 4 batches -> bufT[fout][node] ----
  {
    const half8 w0 = *(const half8*)(wfb + 0 * 1024 + 0 * 512 + lane * 8);
    const half8 w1 = *(const half8*)(wfb + 0 * 1024 + 1 * 512 + lane * 8);
    const float bb0 = bia[lrow], bb1 = bia[16 + lrow];
    const f32x4 bi0 = {bb0, bb0, bb0, bb0};
    const f32x4 bi1 = {bb1, bb1, bb1, bb1};
#pragma unroll
    for (int g = 0; g < 8; ++g) {
#pragma unroll
      for (int ab = 0; ab < 4; ++ab) {
        f16* slab = &smem[ab][0];
        half8 ax = {};
        if (quad == 0) {
          const float* xr = x + ((size_t)(b0 + ab) * N + g * 16 + lrow) * 3;
          union { half8 v8; fp16x2 p[4]; } xa;
          xa.v8 = (half8){};
          xa.p[0] = __builtin_amdgcn_cvt_pkrtz(xr[0], xr[1]);
          xa.p[1] = __builtin_amdgcn_cvt_pkrtz(xr[2], 0.f);
          ax = xa.v8;
        }
        const f32x4 c0 = __builtin_amdgcn_mfma_f32_16x16x32_f16(ax, w0, bi0, 0, 0, 0);
        const f32x4 c1 = __builtin_amdgcn_mfma_f32_16x16x32_f16(ax, w1, bi1, 0, 0, 0);
        *(half4*)(slab + lrow * TS + g * 16 + quad * 4)        = relu4(pk4(c0[0], c0[1], c0[2], c0[3]));
        *(half4*)(slab + (16 + lrow) * TS + g * 16 + quad * 4) = relu4(pk4(c1[0], c1[1], c1[2], c1[3]));
      }
    }
  }

  // ---- G0 -> L1 -> G1 ----
#pragma unroll
  for (int l = 0; l < 2; ++l) {
    // G: P^T = T^T·adj^T for 4 batches; adjf B-frag loaded ONCE per (g,kt)
    {
      half8 aT[4][2][4];
#pragma unroll
      for (int ab = 0; ab < 4; ++ab)
#pragma unroll
        for (int t = 0; t < 2; ++t)
#pragma unroll
          for (int kt = 0; kt < 4; ++kt)
            aT[ab][t][kt] = *(const half8*)(&smem[ab][0] + (t * 16 + lrow) * TS + kt * 32 + quad * 8);
#pragma unroll
      for (int g = 0; g < 8; ++g) {
        f32x4 acc[4][2];
#pragma unroll
        for (int ab = 0; ab < 4; ++ab) { acc[ab][0] = zero; acc[ab][1] = zero; }
#pragma unroll
        for (int kt = 0; kt < 4; ++kt) {
          const half8 bf = *(const half8*)(adjf + (g * 16 + lrow) * N + kt * 32 + quad * 8);
#pragma unroll
          for (int ab = 0; ab < 4; ++ab) {
            acc[ab][0] = __builtin_amdgcn_mfma_f32_16x16x32_f16(aT[ab][0][kt], bf, acc[ab][0], 0, 0, 0);
            acc[ab][1] = __builtin_amdgcn_mfma_f32_16x16x32_f16(aT[ab][1][kt], bf, acc[ab][1], 0, 0, 0);
          }
        }
#pragma unroll
        for (int ab = 0; ab < 4; ++ab) {
          f16* prow = &smem[ab][0] + (g * 16 + lrow) * PS;
          *(half4*)(prow + quad * 4)      = pk4(acc[ab][0][0], acc[ab][0][1], acc[ab][0][2], acc[ab][0][3]);
          *(half4*)(prow + 16 + quad * 4) = pk4(acc[ab][1][0], acc[ab][1][1], acc[ab][1][2], acc[ab][1][3]);
        }
      }
    }
    if (l == 1) break;

    // L1: T1 = relu(P·M0 + c0); preload ALL af (bufP) before bufT overwrites
    {
      half8 af[4][8];
#pragma unroll
      for (int ab = 0; ab < 4; ++ab)
#pragma unroll
        for (int g = 0; g < 8; ++g)
          af[ab][g] = ldp(&smem[ab][0], g * 16 + lrow, quad);
      const half8 w0 = *(const half8*)(wfb + 1 * 1024 + 0 * 512 + lane * 8);
      const half8 w1 = *(const half8*)(wfb + 1 * 1024 + 1 * 512 + lane * 8);
      const float bb0 = bia[H + lrow], bb1 = bia[H + 16 + lrow];
      const f32x4 bi0 = {bb0, bb0, bb0, bb0};
      const f32x4 bi1 = {bb1, bb1, bb1, bb1};
#pragma unroll
      for (int g = 0; g < 8; ++g) {
#pragma unroll
        for (int ab = 0; ab < 4; ++ab) {
          const f32x4 c0 = __builtin_amdgcn_mfma_f32_16x16x32_f16(af[ab][g], w0, bi0, 0, 0, 0);
          const f32x4 c1 = __builtin_amdgcn_mfma_f32_16x16x32_f16(af[ab][g], w1, bi1, 0, 0, 0);
          f16* slab = &smem[ab][0];
          *(half4*)(slab + lrow * TS + g * 16 + quad * 4)        = relu4(pk4(c0[0], c0[1], c0[2], c0[3]));
          *(half4*)(slab + (16 + lrow) * TS + g * 16 + quad * 4) = relu4(pk4(c1[0], c1[1], c1[2], c1[3]));
        }
      }
    }
  }

  // ---- L2 + folded readout for 4 batches ----
  {
    const half8 w0 = *(const half8*)(wfb + 2 * 1024 + 0 * 512 + lane * 8);
    const half8 w1 = *(const half8*)(wfb + 2 * 1024 + 1 * 512 + lane * 8);
    const float bb0 = bia[2 * H + lrow], bb1 = bia[2 * H + 16 + lrow];
    const f32x4 bi0 = {bb0, bb0, bb0, bb0};
    const f32x4 bi1 = {bb1, bb1, bb1, bb1};
    const float u0 = u[lrow], u1 = u[16 + lrow];
    float p[4] = {0.f, 0.f, 0.f, 0.f};
#pragma unroll
    for (int g = 0; g < 8; ++g) {
      const float4 vv = *(const float4*)(v + g * 16 + quad * 4);
#pragma unroll
      for (int ab = 0; ab < 4; ++ab) {
        const half8 af = ldp(&smem[ab][0], g * 16 + lrow, quad);
        const f32x4 c0 = __builtin_amdgcn_mfma_f32_16x16x32_f16(af, w0, bi0, 0, 0, 0);
        const f32x4 c1 = __builtin_amdgcn_mfma_f32_16x16x32_f16(af, w1, bi1, 0, 0, 0);
        p[ab] += (fmaxf(c0[0], 0.f) * vv.x + fmaxf(c0[1], 0.f) * vv.y +
                  fmaxf(c0[2], 0.f) * vv.z + fmaxf(c0[3], 0.f) * vv.w) * u0 +
                 (fmaxf(c1[0], 0.f) * vv.x + fmaxf(c1[1], 0.f) * vv.y +
                  fmaxf(c1[2], 0.f) * vv.z + fmaxf(c1[3], 0.f) * vv.w) * u1;
      }
    }
#pragma unroll
    for (int off = 32; off > 0; off >>= 1) {
#pragma unroll
      for (int ab = 0; ab < 4; ++ab) p[ab] += __shfl_down(p[ab], off, 64);
    }
    if (lane == 0) {
      const float c0 = cp[0];
#pragma unroll
      for (int ab = 0; ab < 4; ++ab) out[b0 + ab] = p[ab] + c0;
    }
  }
}

extern "C" void kernel_launch(void* const* d_in, const int* in_sizes, int n_in,
                              void* d_out, int out_size, void* d_ws, size_t ws_size,
                              hipStream_t stream) {
  const float* x      = (const float*)d_in[0];
  const float* adj    = (const float*)d_in[1];
  const float* W_lift = (const float*)d_in[2];
  const float* b_lift = (const float*)d_in[3];
  const float* W1     = (const float*)d_in[4];
  const float* b1     = (const float*)d_in[5];
  const float* W2     = (const float*)d_in[6];
  const float* b2     = (const float*)d_in[7];
  const float* W_ro   = (const float*)d_in[8];
  const float* b_ro   = (const float*)d_in[9];
  char* ws = (char*)d_ws;
  float* o = (float*)d_out;

  const int B = in_sizes[0] / (N * 3);   // 16384
  hipLaunchKernelGGL(prep, dim3(1), dim3(256), 0, stream,
                     adj, W_lift, b_lift, W1, b1, W2, b2, W_ro, b_ro, ws);
  hipLaunchKernelGGL(gnn_mfma, dim3(B / 4), dim3(64), 0, stream,
                     x, (const char*)ws, o);
}

// Round 14
// 168.567 us; speedup vs baseline: 1.1449x; 1.1449x over previous
//
#include <hip/hip_runtime.h>

// GNN surrogate — f16 MFMA, 2 batches/wave, STAGE-STAGGERED (r14).
// r12 interleaved the two batches inside each stage (lockstep): both chains
// hit every LDS read-after-write boundary simultaneously -> synchronized
// stalls with zero ready work. Here batches advance ALTERNATELY by whole
// stages (L0A,L0B,G0A,G0B,...): each producer->consumer LDS boundary is
// separated by a full independent stage, so one chain's MFMAs fill the
// other's lgkmcnt waits. Same resources as r12: block=128 (2 waves), 4 slabs
// (38912 B -> 4 blocks/CU = 8 waves/CU), launch_bounds(128,2), barrier-free.
// Folds (exact): M_l = W2[l]@W1[l+1] (adj row-normalized -> biases commute
// through aggregation), lift absorbed into W1eff (K=3 pad 32),
// v[j]=mean_i adj[i,j], u=W2[2]@W_ro, cp=(b2[2]·W_ro)*sum(v)+b_ro.

typedef _Float16 f16;
typedef __attribute__((ext_vector_type(8))) _Float16 half8;
typedef __attribute__((ext_vector_type(4))) _Float16 half4;
typedef __attribute__((ext_vector_type(2))) __fp16 fp16x2;   // cvt_pkrtz native
typedef __attribute__((ext_vector_type(4))) float f32x4;

namespace {
constexpr int N = 128, H = 32;
// ws byte layout
constexpr int WS_ADJF = 0;       // f16 [128][128] adj row-major        (32768 B)
constexpr int WS_WFB  = 32768;   // f16 [3][2][64][8] B-frag-ordered Meff (6144 B)
constexpr int WS_BIAS = 38912;   // f32 [3][32] folded biases            (384 B)
constexpr int WS_V    = 39424;   // f32 [128] v[j]=mean_i adj[i][j]      (512 B)
constexpr int WS_U    = 39936;   // f32 [32]  u[k]=sum_c W2[2][k][c]W_ro (128 B)
constexpr int WS_C    = 40064;   // f32 [1]
constexpr int TS = 152;  // bufT row stride f16 (304 B)
constexpr int PS = 36;   // bufP row stride f16 (72 B)
constexpr int SLAB = 4864;       // f16 per slab = 9728 B
}

static __device__ __forceinline__ half4 pk4(float a, float b, float c, float d) {
  union { half4 v; fp16x2 h[2]; } u;
  u.h[0] = __builtin_amdgcn_cvt_pkrtz(a, b);
  u.h[1] = __builtin_amdgcn_cvt_pkrtz(c, d);
  return u.v;
}
static __device__ __forceinline__ half4 relu4(half4 v) {
  const half4 z = {};
  return __builtin_elementwise_max(v, z);
}
static __device__ __forceinline__ half8 ldp(const f16* slab, int row, int quad) {
  union { half8 v; half4 h[2]; } u;
  u.h[0] = *(const half4*)(slab + row * PS + quad * 8);
  u.h[1] = *(const half4*)(slab + row * PS + quad * 8 + 4);
  return u.v;
}

// ---- stages (each fully inlined; slabs disjoint -> scheduler can overlap) --
static __device__ __forceinline__ void stage_L0(
    f16* slab, const float* __restrict__ x, const f16* wfb, const float* bia,
    int b, int lane, int lrow, int quad) {
  const half8 w0 = *(const half8*)(wfb + 0 * 512 + lane * 8);
  const half8 w1 = *(const half8*)(wfb + 1 * 512 + lane * 8);
  const float bb0 = bia[lrow], bb1 = bia[16 + lrow];
  const f32x4 bi0 = {bb0, bb0, bb0, bb0};
  const f32x4 bi1 = {bb1, bb1, bb1, bb1};
#pragma unroll
  for (int g = 0; g < 8; ++g) {
    half8 ax = {};
    if (quad == 0) {
      const float* xr = x + ((size_t)b * N + g * 16 + lrow) * 3;
      union { half8 v8; fp16x2 p[4]; } xa;
      xa.v8 = (half8){};
      xa.p[0] = __builtin_amdgcn_cvt_pkrtz(xr[0], xr[1]);
      xa.p[1] = __builtin_amdgcn_cvt_pkrtz(xr[2], 0.f);
      ax = xa.v8;
    }
    const f32x4 c0 = __builtin_amdgcn_mfma_f32_16x16x32_f16(ax, w0, bi0, 0, 0, 0);
    const f32x4 c1 = __builtin_amdgcn_mfma_f32_16x16x32_f16(ax, w1, bi1, 0, 0, 0);
    *(half4*)(slab + lrow * TS + g * 16 + quad * 4)        = relu4(pk4(c0[0], c0[1], c0[2], c0[3]));
    *(half4*)(slab + (16 + lrow) * TS + g * 16 + quad * 4) = relu4(pk4(c1[0], c1[1], c1[2], c1[3]));
  }
}

static __device__ __forceinline__ void stage_G(
    f16* slab, const f16* __restrict__ adjf, int lrow, int quad) {
  const f32x4 zero = {0.f, 0.f, 0.f, 0.f};
  half8 aT[2][4];
#pragma unroll
  for (int t = 0; t < 2; ++t)
#pragma unroll
    for (int kt = 0; kt < 4; ++kt)
      aT[t][kt] = *(const half8*)(slab + (t * 16 + lrow) * TS + kt * 32 + quad * 8);
#pragma unroll
  for (int g = 0; g < 8; ++g) {
    f32x4 a0 = zero, a1 = zero;
#pragma unroll
    for (int kt = 0; kt < 4; ++kt) {
      const half8 bf = *(const half8*)(adjf + (g * 16 + lrow) * N + kt * 32 + quad * 8);
      a0 = __builtin_amdgcn_mfma_f32_16x16x32_f16(aT[0][kt], bf, a0, 0, 0, 0);
      a1 = __builtin_amdgcn_mfma_f32_16x16x32_f16(aT[1][kt], bf, a1, 0, 0, 0);
    }
    f16* prow = slab + (g * 16 + lrow) * PS;
    *(half4*)(prow + quad * 4)      = pk4(a0[0], a0[1], a0[2], a0[3]);
    *(half4*)(prow + 16 + quad * 4) = pk4(a1[0], a1[1], a1[2], a1[3]);
  }
}

static __device__ __forceinline__ void stage_L1(
    f16* slab, const f16* wfb, const float* bia, int lane, int lrow, int quad) {
  half8 af[8];
#pragma unroll
  for (int g = 0; g < 8; ++g) af[g] = ldp(slab, g * 16 + lrow, quad);
  const half8 w0 = *(const half8*)(wfb + 1024 + 0 * 512 + lane * 8);
  const half8 w1 = *(const half8*)(wfb + 1024 + 1 * 512 + lane * 8);
  const float bb0 = bia[H + lrow], bb1 = bia[H + 16 + lrow];
  const f32x4 bi0 = {bb0, bb0, bb0, bb0};
  const f32x4 bi1 = {bb1, bb1, bb1, bb1};
#pragma unroll
  for (int g = 0; g < 8; ++g) {
    const f32x4 c0 = __builtin_amdgcn_mfma_f32_16x16x32_f16(af[g], w0, bi0, 0, 0, 0);
    const f32x4 c1 = __builtin_amdgcn_mfma_f32_16x16x32_f16(af[g], w1, bi1, 0, 0, 0);
    *(half4*)(slab + lrow * TS + g * 16 + quad * 4)        = relu4(pk4(c0[0], c0[1], c0[2], c0[3]));
    *(half4*)(slab + (16 + lrow) * TS + g * 16 + quad * 4) = relu4(pk4(c1[0], c1[1], c1[2], c1[3]));
  }
}

static __device__ __forceinline__ float stage_L2(
    const f16* slab, const f16* wfb, const float* bia,
    const float* v, const float* u, int lane, int lrow, int quad) {
  const half8 w0 = *(const half8*)(wfb + 2048 + 0 * 512 + lane * 8);
  const half8 w1 = *(const half8*)(wfb + 2048 + 1 * 512 + lane * 8);
  const float bb0 = bia[2 * H + lrow], bb1 = bia[2 * H + 16 + lrow];
  const f32x4 bi0 = {bb0, bb0, bb0, bb0};
  const f32x4 bi1 = {bb1, bb1, bb1, bb1};
  const float u0 = u[lrow], u1 = u[16 + lrow];
  float partial = 0.f;
#pragma unroll
  for (int g = 0; g < 8; ++g) {
    const half8 af = ldp(slab, g * 16 + lrow, quad);
    const f32x4 c0 = __builtin_amdgcn_mfma_f32_16x16x32_f16(af, w0, bi0, 0, 0, 0);
    const f32x4 c1 = __builtin_amdgcn_mfma_f32_16x16x32_f16(af, w1, bi1, 0, 0, 0);
    const float4 vv = *(const float4*)(v + g * 16 + quad * 4);
    partial += (fmaxf(c0[0], 0.f) * vv.x + fmaxf(c0[1], 0.f) * vv.y +
                fmaxf(c0[2], 0.f) * vv.z + fmaxf(c0[3], 0.f) * vv.w) * u0 +
               (fmaxf(c1[0], 0.f) * vv.x + fmaxf(c1[1], 0.f) * vv.y +
                fmaxf(c1[2], 0.f) * vv.z + fmaxf(c1[3], 0.f) * vv.w) * u1;
  }
  return partial;
}

// ---- single-block prep: adj->f16, folded weights/biases, v, u, cp ----
__global__ void prep(const float* __restrict__ adj,
                     const float* __restrict__ W_lift,
                     const float* __restrict__ b_lift,
                     const float* __restrict__ W1,
                     const float* __restrict__ b1,
                     const float* __restrict__ W2,
                     const float* __restrict__ b2,
                     const float* __restrict__ W_ro,
                     const float* __restrict__ b_ro,
                     char* __restrict__ ws) {
  const int tid = threadIdx.x;
  f16* adjf  = (f16*)(ws + WS_ADJF);
  f16* wfb   = (f16*)(ws + WS_WFB);
  float* bia = (float*)(ws + WS_BIAS);
  float* v   = (float*)(ws + WS_V);
  float* u   = (float*)(ws + WS_U);
  float* cp  = (float*)(ws + WS_C);

  {
    const float4* a4 = (const float4*)adj;
#pragma unroll
    for (int r = 0; r < 8; ++r) {
      const int idx = r * 512 + tid * 2;
      const float4 p = a4[idx], q = a4[idx + 1];
      union { half8 v8; fp16x2 h[4]; } o;
      o.h[0] = __builtin_amdgcn_cvt_pkrtz(p.x, p.y);
      o.h[1] = __builtin_amdgcn_cvt_pkrtz(p.z, p.w);
      o.h[2] = __builtin_amdgcn_cvt_pkrtz(q.x, q.y);
      o.h[3] = __builtin_amdgcn_cvt_pkrtz(q.z, q.w);
      *(half8*)(adjf + idx * 4) = o.v8;
    }
  }

  __shared__ float tmp[3][H][H];
  __shared__ float sred[N];
  for (int idx = tid; idx < 3 * H * H; idx += 256) {
    const int l = idx >> 10, rem = idx & 1023;
    const int k = rem >> 5, fo = rem & 31;
    float val = 0.f;
    if (l == 0) {
      if (k < 3) for (int c = 0; c < H; ++c) val += W_lift[k * H + c] * W1[c * H + fo];
    } else {
      const float* w2l = W2 + (l - 1) * H * H;
      const float* w1n = W1 + l * H * H;
      for (int c = 0; c < H; ++c) val += w2l[k * H + c] * w1n[c * H + fo];
    }
    tmp[l][k][fo] = val;
  }
  if (tid < N) {
    float s = 0.f;
    for (int i = 0; i < N; ++i) s += adj[i * N + tid];
    v[tid] = s * (1.0f / N);
    sred[tid] = s * (1.0f / N);
  }
  if (tid < H) {
    float s0 = b1[tid], s1 = b1[H + tid], s2 = b1[2 * H + tid];
    for (int c = 0; c < H; ++c) {
      s0 += b_lift[c] * W1[c * H + tid];
      s1 += b2[c] * W1[H * H + c * H + tid];
      s2 += b2[H + c] * W1[2 * H * H + c * H + tid];
    }
    bia[tid] = s0; bia[H + tid] = s1; bia[2 * H + tid] = s2;
    float su = 0.f;
    for (int c = 0; c < H; ++c) su += W2[2 * H * H + tid * H + c] * W_ro[c];
    u[tid] = su;
  }
  __syncthreads();
  for (int idx = tid; idx < 3 * 1024; idx += 256) {
    const int l = idx >> 10, rem = idx & 1023;
    const int t = rem >> 9, ln = (rem >> 3) & 63, j = rem & 7;
    const int q = ln >> 4, lr = ln & 15;
    wfb[idx] = (f16)tmp[l][q * 8 + j][t * 16 + lr];
  }
  if (tid == 0) {
    float c2r = 0.f;
    for (int k = 0; k < H; ++k) c2r += b2[2 * H + k] * W_ro[k];
    float S = 0.f;
    for (int j = 0; j < N; ++j) S += sred[j];
    cp[0] = c2r * S + b_ro[0];
  }
}

__global__ __launch_bounds__(128, 2)
void gnn_mfma(const float* __restrict__ x,
              const char* __restrict__ ws,
              float* __restrict__ out) {
  __shared__ f16 smem[4][SLAB];   // (2 waves)x(2 batches) slabs = 38912 B

  const f16* adjf  = (const f16*)(ws + WS_ADJF);
  const f16* wfb   = (const f16*)(ws + WS_WFB);
  const float* bia = (const float*)(ws + WS_BIAS);
  const float* v   = (const float*)(ws + WS_V);
  const float* u   = (const float*)(ws + WS_U);
  const float* cp  = (const float*)(ws + WS_C);

  const int tid  = threadIdx.x;
  const int wave = tid >> 6;
  const int lane = tid & 63;
  const int lrow = lane & 15;
  const int quad = lane >> 4;
  const int bA   = blockIdx.x * 4 + wave * 2;
  const int bB   = bA + 1;

  f16* sA = &smem[wave * 2 + 0][0];
  f16* sB = &smem[wave * 2 + 1][0];

  // stage-staggered sequence: every LDS producer->consumer boundary is
  // separated by a full independent stage of the other batch.
  stage_L0(sA, x, wfb, bia, bA, lane, lrow, quad);
  stage_L0(sB, x, wfb, bia, bB, lane, lrow, quad);
  stage_G (sA, adjf, lrow, quad);
  stage_G (sB, adjf, lrow, quad);
  stage_L1(sA, wfb, bia, lane, lrow, quad);
  stage_L1(sB, wfb, bia, lane, lrow, quad);
  stage_G (sA, adjf, lrow, quad);
  stage_G (sB, adjf, lrow, quad);
  float pA = stage_L2(sA, wfb, bia, v, u, lane, lrow, quad);
  float pB = stage_L2(sB, wfb, bia, v, u, lane, lrow, quad);

#pragma unroll
  for (int off = 32; off > 0; off >>= 1) {
    pA += __shfl_down(pA, off, 64);
    pB += __shfl_down(pB, off, 64);
  }
  if (lane == 0) {
    const float c0 = cp[0];
    out[bA] = pA + c0;
    out[bB] = pB + c0;
  }
}

extern "C" void kernel_launch(void* const* d_in, const int* in_sizes, int n_in,
                              void* d_out, int out_size, void* d_ws, size_t ws_size,
                              hipStream_t stream) {
  const float* x      = (const float*)d_in[0];
  const float* adj    = (const float*)d_in[1];
  const float* W_lift = (const float*)d_in[2];
  const float* b_lift = (const float*)d_in[3];
  const float* W1     = (const float*)d_in[4];
  const float* b1     = (const float*)d_in[5];
  const float* W2     = (const float*)d_in[6];
  const float* b2     = (const float*)d_in[7];
  const float* W_ro   = (const float*)d_in[8];
  const float* b_ro   = (const float*)d_in[9];
  char* ws = (char*)d_ws;
  float* o = (float*)d_out;

  const int B = in_sizes[0] / (N * 3);   // 16384
  hipLaunchKernelGGL(prep, dim3(1), dim3(256), 0, stream,
                     adj, W_lift, b_lift, W1, b1, W2, b2, W_ro, b_ro, ws);
  hipLaunchKernelGGL(gnn_mfma, dim3(B / 4), dim3(128), 0, stream,
                     x, (const char*)ws, o);
}